// Round 6
// baseline (168.390 us; speedup 1.0000x reference)
//
#include <hip/hip_runtime.h>
#include <hip/hip_cooperative_groups.h>

namespace cg = cooperative_groups;

// Problem constants: b=32, d=256, h=32, w=128
#define BB 32
#define DD 256
#define HW 4096
#define NSLICE (BB * DD)      // 8192 (b,d) slices of 4096 floats
#define EPS 1e-5f

#define CNBLK 512             // cooperative grid: 2 blocks/CU, wide margin
#define CSPB (NSLICE / CNBLK) // 16 slices per block (one b per block)

typedef float floatx4 __attribute__((ext_vector_type(4)));

// ws layout (floats): [0,8192) slice sum | [8192,16384) slice sumsq | [16384,16416) per-b count
// Every slot is written before the sync point each call -> no zeroing needed.

// ---------------- Fused cooperative kernel ----------------
__global__ void __launch_bounds__(256, 4)
fused_kernel(const float* __restrict__ x, const int* __restrict__ mask,
             const float* __restrict__ gamma, const float* __restrict__ beta,
             float* __restrict__ ws, float* __restrict__ out) {
    const int blk = blockIdx.x;
    const int tid = threadIdx.x;
    const int wave = tid >> 6, lane = tid & 63;
    const int slice0 = blk * CSPB;
    const int b = slice0 >> 8;        // 16 divides 256 -> all 16 slices share b
    const int d0 = slice0 & 255;

    __shared__ float ssum[CSPB][4], ssq[CSPB][4], scnt[4];
    __shared__ float s_scale[CSPB], s_bias[CSPB];

    // Load this b's mask ONCE into registers; reused by phase 1 and phase 3.
    const int4* ms = reinterpret_cast<const int4*>(mask + b * HW);
    int4 mreg[4];
#pragma unroll
    for (int j = 0; j < 4; ++j) mreg[j] = ms[j * 256 + tid];

    // Per-b unmasked count (mask-only, slice-independent)
    float cnt = 0.f;
#pragma unroll
    for (int j = 0; j < 4; ++j) {
        cnt += (mreg[j].x ? 0.f : 1.f) + (mreg[j].y ? 0.f : 1.f)
             + (mreg[j].z ? 0.f : 1.f) + (mreg[j].w ? 0.f : 1.f);
    }
#pragma unroll
    for (int off = 32; off > 0; off >>= 1) cnt += __shfl_down(cnt, off);
    if (lane == 0) scnt[wave] = cnt;

    // ---- Phase 1: per-slice partial sums ----
    const float4* xb = reinterpret_cast<const float4*>(x + (size_t)slice0 * HW);
#pragma unroll
    for (int s = 0; s < CSPB; ++s) {
        float sum = 0.f, sq = 0.f;
#pragma unroll
        for (int j = 0; j < 4; ++j) {
            float4 xv = xb[s * 1024 + j * 256 + tid];
            int4 mv = mreg[j];
            if (!mv.x) { sum += xv.x; sq += xv.x * xv.x; }
            if (!mv.y) { sum += xv.y; sq += xv.y * xv.y; }
            if (!mv.z) { sum += xv.z; sq += xv.z * xv.z; }
            if (!mv.w) { sum += xv.w; sq += xv.w * xv.w; }
        }
#pragma unroll
        for (int off = 32; off > 0; off >>= 1) {
            sum += __shfl_down(sum, off);
            sq  += __shfl_down(sq, off);
        }
        if (lane == 0) { ssum[s][wave] = sum; ssq[s][wave] = sq; }
    }
    __syncthreads();
    if (tid < CSPB) {
        float ts = 0.f, tq = 0.f;
#pragma unroll
        for (int w = 0; w < 4; ++w) { ts += ssum[tid][w]; tq += ssq[tid][w]; }
        ws[slice0 + tid] = ts;
        ws[NSLICE + slice0 + tid] = tq;
    }
    if (tid == 0 && d0 == 0) {
        ws[2 * NSLICE + b] = scnt[0] + scnt[1] + scnt[2] + scnt[3];
    }
    __threadfence();
    cg::this_grid().sync();

    // ---- Phase 2: finalize ONLY this block's 16 channels ----
    // 16 groups of 16 lanes; group c handles channel d0+c; lane l sums b-partials
    // l and l+16 (coalesced-ish, L2-resident, ~4 KB/block).
    {
        const int c = tid >> 4;
        const int l = tid & 15;
        float ps = ws[l * DD + d0 + c]          + ws[(l + 16) * DD + d0 + c];
        float pq = ws[NSLICE + l * DD + d0 + c] + ws[NSLICE + (l + 16) * DD + d0 + c];
        float pc = ws[2 * NSLICE + l]           + ws[2 * NSLICE + l + 16];
#pragma unroll
        for (int off = 8; off > 0; off >>= 1) {
            ps += __shfl_down(ps, off, 16);
            pq += __shfl_down(pq, off, 16);
            pc += __shfl_down(pc, off, 16);
        }
        if (l == 0) {
            pc = fmaxf(pc, 1.0f);
            const float mean = ps / pc;
            const float var = fmaxf(pq / pc - mean * mean, 0.0f);
            const float sc = rsqrtf(var + EPS) * gamma[d0 + c];
            s_scale[c] = sc;
            s_bias[c] = beta[d0 + c] - mean * sc;
        }
    }
    __syncthreads();

    // ---- Phase 3: normalize own slices, reverse order (cache recency) ----
    floatx4* ob = reinterpret_cast<floatx4*>(out + (size_t)slice0 * HW);
#pragma unroll
    for (int s = CSPB - 1; s >= 0; --s) {
        const float sc = s_scale[s], bi = s_bias[s];
#pragma unroll
        for (int j = 0; j < 4; ++j) {
            float4 xv = xb[s * 1024 + j * 256 + tid];
            int4 mv = mreg[j];
            floatx4 o;
            o.x = mv.x ? xv.x : xv.x * sc + bi;
            o.y = mv.y ? xv.y : xv.y * sc + bi;
            o.z = mv.z ? xv.z : xv.z * sc + bi;
            o.w = mv.w ? xv.w : xv.w * sc + bi;
            __builtin_nontemporal_store(o, &ob[s * 1024 + j * 256 + tid]);
        }
    }
}

// ---------------- Fallback: proven two-kernel path (R4, 70.0 us) ----------------
__global__ void __launch_bounds__(256)
stats_kernel(const float* __restrict__ x, const int* __restrict__ mask,
             float* __restrict__ ws) {
    const int slice = blockIdx.x;
    const int b = slice >> 8;
    const int d = slice & 255;
    const float4* xs = reinterpret_cast<const float4*>(
        x + (size_t)b * (DD * HW) + (size_t)d * HW);
    const int4* ms = reinterpret_cast<const int4*>(mask + b * HW);
    const int tid = threadIdx.x;

    float sum = 0.f, sq = 0.f, cnt = 0.f;
#pragma unroll
    for (int j = 0; j < 4; ++j) {
        const int v = j * 256 + tid;
        float4 xv = xs[v];
        int4 mv = ms[v];
        if (!mv.x) { sum += xv.x; sq += xv.x * xv.x; cnt += 1.f; }
        if (!mv.y) { sum += xv.y; sq += xv.y * xv.y; cnt += 1.f; }
        if (!mv.z) { sum += xv.z; sq += xv.z * xv.z; cnt += 1.f; }
        if (!mv.w) { sum += xv.w; sq += xv.w * xv.w; cnt += 1.f; }
    }
#pragma unroll
    for (int off = 32; off > 0; off >>= 1) {
        sum += __shfl_down(sum, off);
        sq  += __shfl_down(sq, off);
        cnt += __shfl_down(cnt, off);
    }
    __shared__ float fsum[4], fsq[4], fcnt[4];
    const int wave = tid >> 6, lane = tid & 63;
    if (lane == 0) { fsum[wave] = sum; fsq[wave] = sq; fcnt[wave] = cnt; }
    __syncthreads();
    if (tid == 0) {
        float ts = 0.f, tq = 0.f, tc = 0.f;
#pragma unroll
        for (int i = 0; i < 4; ++i) { ts += fsum[i]; tq += fsq[i]; tc += fcnt[i]; }
        ws[slice] = ts;
        ws[NSLICE + slice] = tq;
        if (d == 0) ws[2 * NSLICE + b] = tc;
    }
}

__global__ void __launch_bounds__(256)
apply_kernel(const float* __restrict__ x, const int* __restrict__ mask,
             const float* __restrict__ ws, const float* __restrict__ gamma,
             const float* __restrict__ beta, float* __restrict__ out) {
    __shared__ float s_scale[DD], s_bias[DD];
    const int tid = threadIdx.x;

    float cnt = 0.f;
#pragma unroll
    for (int b = 0; b < BB; ++b) cnt += ws[2 * NSLICE + b];
    cnt = fmaxf(cnt, 1.0f);
    float sum = 0.f, sq = 0.f;
#pragma unroll
    for (int b = 0; b < BB; ++b) {
        sum += ws[b * DD + tid];
        sq  += ws[NSLICE + b * DD + tid];
    }
    const float mean = sum / cnt;
    const float var = fmaxf(sq / cnt - mean * mean, 0.0f);
    const float sc = rsqrtf(var + EPS) * gamma[tid];
    s_scale[tid] = sc;
    s_bias[tid] = beta[tid] - mean * sc;
    __syncthreads();

    const int nvec = (BB * DD * HW) / 4;
    const int stride = gridDim.x * blockDim.x;
    floatx4* __restrict__ ov = reinterpret_cast<floatx4*>(out);
    for (int v = blockIdx.x * blockDim.x + tid; v < nvec; v += stride) {
        const int e = v << 2;
        const int bidx = e >> 20;
        const int rem = e & (DD * HW - 1);
        const int d = rem >> 12;
        const int pos = rem & 4095;
        float4 xv = reinterpret_cast<const float4*>(x)[v];
        int4 mv = reinterpret_cast<const int4*>(mask)[(bidx * HW + pos) >> 2];
        const float s = s_scale[d], bi = s_bias[d];
        floatx4 o;
        o.x = mv.x ? xv.x : xv.x * s + bi;
        o.y = mv.y ? xv.y : xv.y * s + bi;
        o.z = mv.z ? xv.z : xv.z * s + bi;
        o.w = mv.w ? xv.w : xv.w * s + bi;
        __builtin_nontemporal_store(o, &ov[v]);
    }
}

extern "C" void kernel_launch(void* const* d_in, const int* in_sizes, int n_in,
                              void* d_out, int out_size, void* d_ws, size_t ws_size,
                              hipStream_t stream) {
    const float* x     = (const float*)d_in[0];
    const int*   mask  = (const int*)d_in[1];
    const float* gamma = (const float*)d_in[2];
    const float* beta  = (const float*)d_in[3];
    float* out = (float*)d_out;
    float* ws  = (float*)d_ws;

    void* args[] = {(void*)&x, (void*)&mask, (void*)&gamma, (void*)&beta,
                    (void*)&ws, (void*)&out};
    hipError_t err = hipLaunchCooperativeKernel((const void*)fused_kernel,
                                                dim3(CNBLK), dim3(256),
                                                args, 0, stream);
    if (err != hipSuccess) {
        // Deterministic fallback: proven two-kernel path.
        stats_kernel<<<NSLICE, 256, 0, stream>>>(x, mask, ws);
        apply_kernel<<<2048, 256, 0, stream>>>(x, mask, ws, gamma, beta, out);
    }
}